// Round 5
// baseline (1106.758 us; speedup 1.0000x reference)
//
#include <hip/hip_runtime.h>
#include <stdint.h>

#define R_NODES 256
#define M_SAMP  512
#define S_STEPS 512
#define OUT_N   10

typedef unsigned int u32x2 __attribute__((ext_vector_type(2)));

// ---------------- layout detection for bool inputs ----------------
// If bools were uploaded as int32, byte (4f+1) of every element is 0.
// If uploaded as uint8, ~half those bytes are 1.  flag=1 => uint8 layout.
__global__ void detect_layout(const uint8_t* __restrict__ x, int* __restrict__ flag) {
    __shared__ int any;
    if (threadIdx.x == 0) any = 0;
    __syncthreads();
    int acc = 0;
    for (int i = 0; i < 64; ++i)
        acc |= x[(size_t)(threadIdx.x * 64 + i) * 4 + 1];
    if (acc) atomicOr(&any, 1);
    __syncthreads();
    if (threadIdx.x == 0) *flag = any ? 1 : 0;
}

// ---------------- pack x bits: one uint32 per (m,s) ----------------
__global__ void pack_x(const uint8_t* __restrict__ x, const int* __restrict__ flag,
                       uint32_t* __restrict__ xp) {
    const int stride = (*flag) ? 1 : 4;
    const int f = blockIdx.x * blockDim.x + threadIdx.x;      // element idx, M*S*32 total
    const int val = x[(size_t)f * stride];
    const uint64_t mask = __ballot(val != 0);
    const int lane = threadIdx.x & 63;
    if ((lane & 31) == 0) {
        uint32_t w = (lane & 32) ? (uint32_t)(mask >> 32) : (uint32_t)mask;
        xp[f >> 5] = w;
    }
}

// ---------------- build nibble-chunk partial-sum table ----------------
// T1[(v*64 + c)*256 + j] = sum_{p:bit p of v} primes[4c+p] * W[j][4c+p]
// 16 vals x 64 chunks x 256 nodes x u16 = 512 KB -> L2-resident (4MB/XCD).
// Chunk c covers nodes 4c..4c+3 == lane c's own state bits in the main
// kernel, so the table index is LANE-LOCAL (no ballots needed).
// Per-chunk max sum <= 4*1619 = 6476; any 8-chunk group <= 48.7K < 2^16,
// so packed-u16 group accumulation cannot overflow.
__global__ void build_T1(const uint8_t* __restrict__ wres, const int* __restrict__ primes,
                         const int* __restrict__ flag, uint16_t* __restrict__ T1) {
    const int v = blockIdx.x;          // 0..15 nibble value
    const int c = blockIdx.y;          // 0..63 chunk
    const int j = threadIdx.x;         // 0..255 node
    const int stride = (*flag) ? 1 : 4;
    int sum = 0;
#pragma unroll
    for (int p = 0; p < 4; ++p) {
        if ((v >> p) & 1) {
            const int k = c * 4 + p;
            if (wres[(size_t)(j * 256 + k) * stride]) sum += primes[k];
        }
    }
    T1[((size_t)v * 64 + c) * 256 + j] = (uint16_t)sum;
}

// ---------------- bit-pack the LUT: 256MB int32 -> 8MB bits ----------------
__device__ __forceinline__ uint32_t spread8(uint32_t x) {
    // bit i of low byte -> bit 4*i
    x = (x | (x << 12)) & 0x000F000Fu;
    x = (x | (x << 6))  & 0x03030303u;
    x = (x | (x << 3))  & 0x11111111u;
    return x;
}
__global__ void pack_lut(const int* __restrict__ lut, uint32_t* __restrict__ lp32) {
    const int lane = threadIdx.x & 63;
    const int gw = blockIdx.x * (blockDim.x >> 6) + (threadIdx.x >> 6); // 16384 waves
    const int4* src = (const int4*)lut;
    for (int it = 0; it < 16; ++it) {
        const int chunk = gw * 16 + it;                // 262144 wave-chunks total
        const int4 q = src[(size_t)chunk * 64 + lane]; // coalesced 16B/lane
        const uint64_t b0 = __ballot((q.x & 1) != 0);
        const uint64_t b1 = __ballot((q.y & 1) != 0);
        const uint64_t b2 = __ballot((q.z & 1) != 0);
        const uint64_t b3 = __ballot((q.w & 1) != 0);
        if (lane < 8) {
            const uint32_t B0 = (uint32_t)(b0 >> (8 * lane)) & 0xFF;
            const uint32_t B1 = (uint32_t)(b1 >> (8 * lane)) & 0xFF;
            const uint32_t B2 = (uint32_t)(b2 >> (8 * lane)) & 0xFF;
            const uint32_t B3 = (uint32_t)(b3 >> (8 * lane)) & 0xFF;
            const uint32_t w = spread8(B0) | (spread8(B1) << 1)
                             | (spread8(B2) << 2) | (spread8(B3) << 3);
            lp32[(size_t)chunk * 8 + lane] = w;
        }
    }
}

// ---------------- main reservoir scan: ONE WAVE per sample ----------------
// 512 blocks x 64 threads; lane l owns nodes 4l..4l+3.
// Nibble-chunk structure: chunk c == lane c's own 4 state bits, so the
// table row index vtmp = (val<<15)|(l<<9) is computed WITHOUT ballots.
// Per step: 64 asm gathers (readlane row offset -> v_add with lane col
// offset -> global_load_dwordx2 off fixed SGPR base), mid-issue vmcnt(40)
// caps outstanding <=56 (<63 counter limit), staged vmcnt(56..0) group
// waits overlap the packed-u16 reduce with the tail latency, then 4 asm
// lp loads + vmcnt(0).  xw comes from LDS (preloaded; lgkmcnt) so the
// vmcnt counting stays exact: EVERY in-loop VMEM op is ours.
__global__ __launch_bounds__(64, 1) void reservoir_wave(
    const uint32_t* __restrict__ xp, const uint16_t* __restrict__ T1,
    const uint64_t* __restrict__ lp, const int* __restrict__ input_nodes,
    const uint8_t* __restrict__ init_res, const int* __restrict__ flag,
    const float* __restrict__ rW, const float* __restrict__ rb,
    float* __restrict__ out)
{
    const int m = blockIdx.x;
    const int l = threadIdx.x;          // lane 0..63
    const int stride = (*flag) ? 1 : 4;

    __shared__ uint32_t sxw[S_STEPS];
    const uint32_t* xrow = xp + m * S_STEPS;
    for (int i = l; i < S_STEPS; i += 64) sxw[i] = xrow[i];

    // input-slot assignment for this lane's 4 nodes
    int slot0 = -1, slot1 = -1, slot2 = -1, slot3 = -1;
    for (int i = 0; i < 32; ++i) {
        const int n = input_nodes[i];
        if (n == 4 * l + 0) slot0 = i;
        if (n == 4 * l + 1) slot1 = i;
        if (n == 4 * l + 2) slot2 = i;
        if (n == 4 * l + 3) slot3 = i;
    }
    int v0 = init_res[(size_t)(4 * l + 0) * stride] ? 1 : 0;
    int v1 = init_res[(size_t)(4 * l + 1) * stride] ? 1 : 0;
    int v2 = init_res[(size_t)(4 * l + 2) * stride] ? 1 : 0;
    int v3 = init_res[(size_t)(4 * l + 3) * stride] ? 1 : 0;

    const uint64_t t1base = (uint64_t)(uintptr_t)T1;
    const uint64_t lpbase = (uint64_t)(uintptr_t)lp;
    const uint32_t lane8  = (uint32_t)(l << 3);    // byte col offset: 4 u16
    const uint32_t nb     = (uint32_t)l << 17;     // lp byte base of node 4l

    __syncthreads();
    uint32_t xw = sxw[0];

#define LOADC(c) do {                                                         \
        const int so_ = __builtin_amdgcn_readlane((int)vtmp, (c));            \
        const uint32_t vo_ = (uint32_t)so_ + lane8;                           \
        asm volatile("global_load_dwordx2 %0, %1, %2"                         \
                     : "=v"(d[(c)]) : "v"(vo_), "s"(t1base));                 \
    } while (0)

#define GROUP(g, WAITSTR) do {                                                \
        asm volatile(WAITSTR);                                                \
        asm volatile("" : "+v"(d[8*(g)+0]), "+v"(d[8*(g)+1]),                 \
                          "+v"(d[8*(g)+2]), "+v"(d[8*(g)+3]),                 \
                          "+v"(d[8*(g)+4]), "+v"(d[8*(g)+5]),                 \
                          "+v"(d[8*(g)+6]), "+v"(d[8*(g)+7]));                \
        const uint32_t lo_ = d[8*(g)+0][0] + d[8*(g)+1][0] + d[8*(g)+2][0]    \
                           + d[8*(g)+3][0] + d[8*(g)+4][0] + d[8*(g)+5][0]    \
                           + d[8*(g)+6][0] + d[8*(g)+7][0];                   \
        const uint32_t hi_ = d[8*(g)+0][1] + d[8*(g)+1][1] + d[8*(g)+2][1]    \
                           + d[8*(g)+3][1] + d[8*(g)+4][1] + d[8*(g)+5][1]    \
                           + d[8*(g)+6][1] + d[8*(g)+7][1];                   \
        i0 += lo_ & 0xFFFFu;  i1 += lo_ >> 16;                                \
        i2 += hi_ & 0xFFFFu;  i3 += hi_ >> 16;                                \
    } while (0)

    for (int s = 0; s < S_STEPS; ++s) {
        if (slot0 >= 0) v0 = (xw >> slot0) & 1;
        if (slot1 >= 0) v1 = (xw >> slot1) & 1;
        if (slot2 >= 0) v2 = (xw >> slot2) & 1;
        if (slot3 >= 0) v3 = (xw >> slot3) & 1;

        // lane-local nibble -> table row byte offset (row = val*64 + l)
        const uint32_t val = (uint32_t)v0 | ((uint32_t)v1 << 1)
                           | ((uint32_t)v2 << 2) | ((uint32_t)v3 << 3);
        const int vtmp = (int)((val << 15) | ((uint32_t)l << 9));

        // ---- phase 1: issue 64 row gathers (cap in-flight at 56 < 63) ----
        u32x2 d[64];
#pragma unroll
        for (int c = 0; c < 48; ++c) LOADC(c);
        asm volatile("s_waitcnt vmcnt(40)");
#pragma unroll
        for (int c = 48; c < 64; ++c) LOADC(c);

        // next step's input word via LDS (lgkmcnt; invisible to vmcnt)
        const uint32_t xw_next = sxw[(s + 1 < S_STEPS) ? s + 1 : s];

        // ---- phase 2: staged waits + packed u16x2 reduce ----
        uint32_t i0 = 0, i1 = 0, i2 = 0, i3 = 0;
        GROUP(0, "s_waitcnt vmcnt(56)");
        GROUP(1, "s_waitcnt vmcnt(48)");
        GROUP(2, "s_waitcnt vmcnt(40)");
        GROUP(3, "s_waitcnt vmcnt(32)");
        GROUP(4, "s_waitcnt vmcnt(24)");
        GROUP(5, "s_waitcnt vmcnt(16)");
        GROUP(6, "s_waitcnt vmcnt(8)");
        GROUP(7, "s_waitcnt vmcnt(0)");

        // ---- phase 3: 4 independent LUT-bit loads (asm, counted) ---------
        u32x2 w0, w1, w2, w3;
        const uint32_t o0 = nb             + ((i0 >> 6) << 3);
        const uint32_t o1 = nb + (1 << 15) + ((i1 >> 6) << 3);
        const uint32_t o2 = nb + (2 << 15) + ((i2 >> 6) << 3);
        const uint32_t o3 = nb + (3 << 15) + ((i3 >> 6) << 3);
        asm volatile("global_load_dwordx2 %0, %1, %2" : "=v"(w0) : "v"(o0), "s"(lpbase));
        asm volatile("global_load_dwordx2 %0, %1, %2" : "=v"(w1) : "v"(o1), "s"(lpbase));
        asm volatile("global_load_dwordx2 %0, %1, %2" : "=v"(w2) : "v"(o2), "s"(lpbase));
        asm volatile("global_load_dwordx2 %0, %1, %2" : "=v"(w3) : "v"(o3), "s"(lpbase));
        asm volatile("s_waitcnt vmcnt(0)");
        asm volatile("" : "+v"(w0), "+v"(w1), "+v"(w2), "+v"(w3));

        v0 = (int)(((((uint64_t)w0[1] << 32) | w0[0]) >> (i0 & 63)) & 1);
        v1 = (int)(((((uint64_t)w1[1] << 32) | w1[0]) >> (i1 & 63)) & 1);
        v2 = (int)(((((uint64_t)w2[1] << 32) | w2[0]) >> (i2 & 63)) & 1);
        v3 = (int)(((((uint64_t)w3[1] << 32) | w3[0]) >> (i3 & 63)) & 1);
        xw = xw_next;
    }
#undef LOADC
#undef GROUP

    // keep the readout loads from being hoisted into the counted loop
    const float* rWo;
    const float* rbo;
    asm volatile("" : "=s"(rWo) : "0"(rW));
    asm volatile("" : "=s"(rbo) : "0"(rb));

    // readout: out[m][o] = b[o] + sum_j v_j * W[o][j]  (wave shuffle reduce)
#pragma unroll
    for (int o = 0; o < OUT_N; ++o) {
        const float* wrow = rWo + o * R_NODES + 4 * l;
        float c = 0.f;
        if (v0) c += wrow[0];
        if (v1) c += wrow[1];
        if (v2) c += wrow[2];
        if (v3) c += wrow[3];
#pragma unroll
        for (int off = 32; off > 0; off >>= 1)
            c += __shfl_down(c, off, 64);
        if (l == 0) out[m * OUT_N + o] = c + rbo[o];
    }
}

extern "C" void kernel_launch(void* const* d_in, const int* in_sizes, int n_in,
                              void* d_out, int out_size, void* d_ws, size_t ws_size,
                              hipStream_t stream) {
    const uint8_t* x        = (const uint8_t*)d_in[0];   // bool [M,S,D,B]
    const int* input_nodes  = (const int*)d_in[1];       // int32 [32]
    const int* lut          = (const int*)d_in[2];       // int32 [256, 2^18]
    const uint8_t* wres     = (const uint8_t*)d_in[3];   // bool [256,256]
    const int* primes       = (const int*)d_in[4];       // int32 [256]
    const uint8_t* init_res = (const uint8_t*)d_in[5];   // bool [256]
    const float* rW         = (const float*)d_in[6];     // f32 [10,256]
    const float* rb         = (const float*)d_in[7];     // f32 [10]
    float* out              = (float*)d_out;             // f32 [512,10]

    uint8_t* ws = (uint8_t*)d_ws;
    int*      flag = (int*)ws;                                        // 4 B
    uint32_t* xp   = (uint32_t*)(ws + 4096);                          // 1 MB
    uint16_t* T1   = (uint16_t*)(ws + 4096 + 1048576);                // 512 KB
    uint64_t* lp   = (uint64_t*)(ws + 4096 + 1048576 + 524288);       // 8 MB

    detect_layout<<<1, 256, 0, stream>>>(x, flag);
    pack_x<<<(M_SAMP * S_STEPS * 32) / 256, 256, 0, stream>>>(x, flag, xp);
    build_T1<<<dim3(16, 64), 256, 0, stream>>>(wres, primes, flag, T1);
    pack_lut<<<4096, 256, 0, stream>>>(lut, (uint32_t*)lp);
    reservoir_wave<<<M_SAMP, 64, 0, stream>>>(xp, T1, lp, input_nodes, init_res,
                                              flag, rW, rb, out);
}

// Round 6
// 1076.246 us; speedup vs baseline: 1.0284x; 1.0284x over previous
//
#include <hip/hip_runtime.h>
#include <stdint.h>

#define R_NODES 256
#define M_SAMP  512
#define S_STEPS 512
#define OUT_N   10

typedef unsigned int u32x2 __attribute__((ext_vector_type(2)));
typedef unsigned int u32x4 __attribute__((ext_vector_type(4)));

// ---------------- layout detection for bool inputs ----------------
// If bools were uploaded as int32, byte (4f+1) of every element is 0.
// If uploaded as uint8, ~half those bytes are 1.  flag=1 => uint8 layout.
__global__ void detect_layout(const uint8_t* __restrict__ x, int* __restrict__ flag) {
    __shared__ int any;
    if (threadIdx.x == 0) any = 0;
    __syncthreads();
    int acc = 0;
    for (int i = 0; i < 64; ++i)
        acc |= x[(size_t)(threadIdx.x * 64 + i) * 4 + 1];
    if (acc) atomicOr(&any, 1);
    __syncthreads();
    if (threadIdx.x == 0) *flag = any ? 1 : 0;
}

// ---------------- pack x bits: one uint32 per (m,s) ----------------
__global__ void pack_x(const uint8_t* __restrict__ x, const int* __restrict__ flag,
                       uint32_t* __restrict__ xp) {
    const int stride = (*flag) ? 1 : 4;
    const int f = blockIdx.x * blockDim.x + threadIdx.x;      // element idx, M*S*32 total
    const int val = x[(size_t)f * stride];
    const uint64_t mask = __ballot(val != 0);
    const int lane = threadIdx.x & 63;
    if ((lane & 31) == 0) {
        uint32_t w = (lane & 32) ? (uint32_t)(mask >> 32) : (uint32_t)mask;
        xp[f >> 5] = w;
    }
}

// ---------------- build byte-chunk partial-sum table (IDENTITY bits) ----
// T2[(v*32 + c)*256 + j] = sum_{p: bit p of v} primes[c*8+p] * W[j][c*8+p]
// Identity bit map: main kernel's node ownership n0(l) = l<32 ? 8l : 8(l-32)+4
// makes byte u_C for chunk C assemble as bit p = state of node 8C+p directly
// from ballot words.  Per-chunk max sum ~12.9K (u16 safe); any 4-chunk
// group <= 51808 < 2^16: packed-u16 adds can't overflow.
__global__ void build_T2(const uint8_t* __restrict__ wres, const int* __restrict__ primes,
                         const int* __restrict__ flag, uint16_t* __restrict__ T2) {
    const int v = blockIdx.x;          // 0..255 byte value
    const int c = blockIdx.y;          // 0..31 chunk
    const int j = threadIdx.x;         // 0..255 node
    const int stride = (*flag) ? 1 : 4;
    int sum = 0;
#pragma unroll
    for (int p = 0; p < 8; ++p) {
        if ((v >> p) & 1) {
            const int k = c * 8 + p;
            if (wres[(size_t)(j * 256 + k) * stride]) sum += primes[k];
        }
    }
    T2[((size_t)v * 32 + c) * 256 + j] = (uint16_t)sum;
}

// ---------------- bit-pack the LUT: 256MB int32 -> 8MB bits ----------------
__device__ __forceinline__ uint32_t spread8(uint32_t x) {
    // bit i of low byte -> bit 4*i
    x = (x | (x << 12)) & 0x000F000Fu;
    x = (x | (x << 6))  & 0x03030303u;
    x = (x | (x << 3))  & 0x11111111u;
    return x;
}
__global__ void pack_lut(const int* __restrict__ lut, uint32_t* __restrict__ lp32) {
    const int lane = threadIdx.x & 63;
    const int gw = blockIdx.x * (blockDim.x >> 6) + (threadIdx.x >> 6); // 16384 waves
    const int4* src = (const int4*)lut;
    for (int it = 0; it < 16; ++it) {
        const int chunk = gw * 16 + it;                // 262144 wave-chunks total
        const int4 q = src[(size_t)chunk * 64 + lane]; // coalesced 16B/lane
        const uint64_t b0 = __ballot((q.x & 1) != 0);
        const uint64_t b1 = __ballot((q.y & 1) != 0);
        const uint64_t b2 = __ballot((q.z & 1) != 0);
        const uint64_t b3 = __ballot((q.w & 1) != 0);
        if (lane < 8) {
            const uint32_t B0 = (uint32_t)(b0 >> (8 * lane)) & 0xFF;
            const uint32_t B1 = (uint32_t)(b1 >> (8 * lane)) & 0xFF;
            const uint32_t B2 = (uint32_t)(b2 >> (8 * lane)) & 0xFF;
            const uint32_t B3 = (uint32_t)(b3 >> (8 * lane)) & 0xFF;
            const uint32_t w = spread8(B0) | (spread8(B1) << 1)
                             | (spread8(B2) << 2) | (spread8(B3) << 3);
            lp32[(size_t)chunk * 8 + lane] = w;
        }
    }
}

// ---------------- main reservoir scan: ONE WAVE per sample ----------------
// 512 blocks x 64 threads.  Node ownership: lane l owns 4 contiguous nodes
// n0..n0+3 with n0 = l<32 ? 8l : 8(l-32)+4  (lanes B and B+32 together own
// the byte-chunk B's 8 nodes).
// R4/R5 evidence: per-wave VMEM concurrency is capped (~4 instrs / ~16
// lines in flight) -> stall ~= (instrs/4) x latency.  So: FEWER, FATTER
// instructions.  Per step: 16 x global_load_dwordx4, instruction i reads
// table rows for chunks 2i (lanes 0-31) and 2i+1 (lanes 32-63), each lane
// a 16B col-block (cols 8(l&31)..+7).  Lane B accumulates even chunks,
// lane B+32 odd chunks; one shfl_xor(32) combine yields full col sums,
// half-select maps them onto each lane's own 4 nodes.  No LDS/barriers.
__global__ __launch_bounds__(64, 1) void reservoir_wave(
    const uint32_t* __restrict__ xp, const uint16_t* __restrict__ T2,
    const uint64_t* __restrict__ lp, const int* __restrict__ input_nodes,
    const uint8_t* __restrict__ init_res, const int* __restrict__ flag,
    const float* __restrict__ rW, const float* __restrict__ rb,
    float* __restrict__ out)
{
    const int m = blockIdx.x;
    const int l = threadIdx.x;          // lane 0..63
    const int stride = (*flag) ? 1 : 4;
    const bool lohalf = (l < 32);
    const int n0 = lohalf ? (l << 3) : (((l - 32) << 3) + 4);

    __shared__ uint32_t sxw[S_STEPS];
    const uint32_t* xrow = xp + m * S_STEPS;
    for (int i = l; i < S_STEPS; i += 64) sxw[i] = xrow[i];

    // input-slot assignment for this lane's 4 nodes
    int slot0 = -1, slot1 = -1, slot2 = -1, slot3 = -1;
    for (int i = 0; i < 32; ++i) {
        const int n = input_nodes[i];
        if (n == n0 + 0) slot0 = i;
        if (n == n0 + 1) slot1 = i;
        if (n == n0 + 2) slot2 = i;
        if (n == n0 + 3) slot3 = i;
    }
    int v0 = init_res[(size_t)(n0 + 0) * stride] ? 1 : 0;
    int v1 = init_res[(size_t)(n0 + 1) * stride] ? 1 : 0;
    int v2 = init_res[(size_t)(n0 + 2) * stride] ? 1 : 0;
    int v3 = init_res[(size_t)(n0 + 3) * stride] ? 1 : 0;

    const uint64_t t2base = (uint64_t)(uintptr_t)T2;
    const uint64_t lpbase = (uint64_t)(uintptr_t)lp;
    const uint32_t colb   = (uint32_t)((l & 31) << 4);  // 16B col-block offset
    const uint32_t nb     = (uint32_t)n0 << 15;         // lp byte base of node n0

    __syncthreads();
    uint32_t xw = sxw[0];

#define LOADI(i) do {                                                         \
        const int se_ = __builtin_amdgcn_readlane((int)roff, 2*(i));          \
        const int so_ = __builtin_amdgcn_readlane((int)roff, 2*(i)+1);        \
        const uint32_t sel_ = lohalf ? (uint32_t)se_ : (uint32_t)so_;         \
        asm volatile("global_load_dwordx4 %0, %1, %2"                         \
                     : "=v"(d[(i)]) : "v"(sel_ + colb), "s"(t2base));         \
    } while (0)

#define GROUP(g, WAITSTR) do {                                                \
        asm volatile(WAITSTR);                                                \
        asm volatile("" : "+v"(d[4*(g)+0]), "+v"(d[4*(g)+1]),                 \
                          "+v"(d[4*(g)+2]), "+v"(d[4*(g)+3]));                \
        const uint32_t px = d[4*(g)+0][0] + d[4*(g)+1][0] + d[4*(g)+2][0] + d[4*(g)+3][0]; \
        const uint32_t py = d[4*(g)+0][1] + d[4*(g)+1][1] + d[4*(g)+2][1] + d[4*(g)+3][1]; \
        const uint32_t pz = d[4*(g)+0][2] + d[4*(g)+1][2] + d[4*(g)+2][2] + d[4*(g)+3][2]; \
        const uint32_t pw = d[4*(g)+0][3] + d[4*(g)+1][3] + d[4*(g)+2][3] + d[4*(g)+3][3]; \
        a0 += px & 0xFFFFu;  a1 += px >> 16;                                  \
        a2 += py & 0xFFFFu;  a3 += py >> 16;                                  \
        a4 += pz & 0xFFFFu;  a5 += pz >> 16;                                  \
        a6 += pw & 0xFFFFu;  a7 += pw >> 16;                                  \
    } while (0)

    for (int s = 0; s < S_STEPS; ++s) {
        if (slot0 >= 0) v0 = (xw >> slot0) & 1;
        if (slot1 >= 0) v1 = (xw >> slot1) & 1;
        if (slot2 >= 0) v2 = (xw >> slot2) & 1;
        if (slot3 >= 0) v3 = (xw >> slot3) & 1;

        const uint64_t b0 = __ballot(v0 != 0);
        const uint64_t b1 = __ballot(v1 != 0);
        const uint64_t b2 = __ballot(v2 != 0);
        const uint64_t b3 = __ballot(v3 != 0);

        // byte for chunk C = l&31: bit p = state of node 8C+p (identity map)
        const uint32_t C = (uint32_t)(l & 31);
        const uint32_t u = (((uint32_t)(b0        ) >> C) & 1u)
                         | ((((uint32_t)(b1       ) >> C) & 1u) << 1)
                         | ((((uint32_t)(b2       ) >> C) & 1u) << 2)
                         | ((((uint32_t)(b3       ) >> C) & 1u) << 3)
                         | ((((uint32_t)(b0 >> 32) >> C) & 1u) << 4)
                         | ((((uint32_t)(b1 >> 32) >> C) & 1u) << 5)
                         | ((((uint32_t)(b2 >> 32) >> C) & 1u) << 6)
                         | ((((uint32_t)(b3 >> 32) >> C) & 1u) << 7);
        // lane C holds its chunk's row byte offset: (u*32 + C) * 512
        const uint32_t roff = (u << 14) | (C << 9);

        // ---- phase 1: 16 x dwordx4 (2 table rows per instruction) --------
        u32x4 d[16];
#pragma unroll
        for (int i = 0; i < 16; ++i) LOADI(i);

        // next step's input word via LDS (lgkmcnt; invisible to vmcnt)
        const uint32_t xw_next = sxw[(s + 1 < S_STEPS) ? s + 1 : s];

        // ---- phase 2: staged waits + packed u16x2 accumulate + widen -----
        uint32_t a0 = 0, a1 = 0, a2 = 0, a3 = 0, a4 = 0, a5 = 0, a6 = 0, a7 = 0;
        GROUP(0, "s_waitcnt vmcnt(12)");
        GROUP(1, "s_waitcnt vmcnt(8)");
        GROUP(2, "s_waitcnt vmcnt(4)");
        GROUP(3, "s_waitcnt vmcnt(0)");

        // combine halves: lane B has even chunks, lane B+32 odd chunks
        const uint32_t t0 = a0 + __shfl_xor(a0, 32, 64);
        const uint32_t t1 = a1 + __shfl_xor(a1, 32, 64);
        const uint32_t t2 = a2 + __shfl_xor(a2, 32, 64);
        const uint32_t t3 = a3 + __shfl_xor(a3, 32, 64);
        const uint32_t t4 = a4 + __shfl_xor(a4, 32, 64);
        const uint32_t t5 = a5 + __shfl_xor(a5, 32, 64);
        const uint32_t t6 = a6 + __shfl_xor(a6, 32, 64);
        const uint32_t t7 = a7 + __shfl_xor(a7, 32, 64);

        // own-node selection: lo half -> cols 8B..8B+3, hi half -> 8B+4..+7
        const uint32_t i0 = lohalf ? t0 : t4;
        const uint32_t i1 = lohalf ? t1 : t5;
        const uint32_t i2 = lohalf ? t2 : t6;
        const uint32_t i3 = lohalf ? t3 : t7;

        // ---- phase 3: 4 independent LUT-bit loads (asm, counted) ---------
        u32x2 w0, w1, w2, w3;
        const uint32_t o0 = nb             + ((i0 >> 6) << 3);
        const uint32_t o1 = nb + (1 << 15) + ((i1 >> 6) << 3);
        const uint32_t o2 = nb + (2 << 15) + ((i2 >> 6) << 3);
        const uint32_t o3 = nb + (3 << 15) + ((i3 >> 6) << 3);
        asm volatile("global_load_dwordx2 %0, %1, %2" : "=v"(w0) : "v"(o0), "s"(lpbase));
        asm volatile("global_load_dwordx2 %0, %1, %2" : "=v"(w1) : "v"(o1), "s"(lpbase));
        asm volatile("global_load_dwordx2 %0, %1, %2" : "=v"(w2) : "v"(o2), "s"(lpbase));
        asm volatile("global_load_dwordx2 %0, %1, %2" : "=v"(w3) : "v"(o3), "s"(lpbase));
        asm volatile("s_waitcnt vmcnt(0)");
        asm volatile("" : "+v"(w0), "+v"(w1), "+v"(w2), "+v"(w3));

        v0 = (int)(((((uint64_t)w0[1] << 32) | w0[0]) >> (i0 & 63)) & 1);
        v1 = (int)(((((uint64_t)w1[1] << 32) | w1[0]) >> (i1 & 63)) & 1);
        v2 = (int)(((((uint64_t)w2[1] << 32) | w2[0]) >> (i2 & 63)) & 1);
        v3 = (int)(((((uint64_t)w3[1] << 32) | w3[0]) >> (i3 & 63)) & 1);
        xw = xw_next;
    }
#undef LOADI
#undef GROUP

    // keep the readout loads from being hoisted into the counted loop
    const float* rWo;
    const float* rbo;
    asm volatile("" : "=s"(rWo) : "0"(rW));
    asm volatile("" : "=s"(rbo) : "0"(rb));

    // readout: out[m][o] = b[o] + sum_j v_j * W[o][j]  (wave shuffle reduce)
#pragma unroll
    for (int o = 0; o < OUT_N; ++o) {
        const float* wrow = rWo + o * R_NODES + n0;
        float c = 0.f;
        if (v0) c += wrow[0];
        if (v1) c += wrow[1];
        if (v2) c += wrow[2];
        if (v3) c += wrow[3];
#pragma unroll
        for (int off = 32; off > 0; off >>= 1)
            c += __shfl_down(c, off, 64);
        if (l == 0) out[m * OUT_N + o] = c + rbo[o];
    }
}

extern "C" void kernel_launch(void* const* d_in, const int* in_sizes, int n_in,
                              void* d_out, int out_size, void* d_ws, size_t ws_size,
                              hipStream_t stream) {
    const uint8_t* x        = (const uint8_t*)d_in[0];   // bool [M,S,D,B]
    const int* input_nodes  = (const int*)d_in[1];       // int32 [32]
    const int* lut          = (const int*)d_in[2];       // int32 [256, 2^18]
    const uint8_t* wres     = (const uint8_t*)d_in[3];   // bool [256,256]
    const int* primes       = (const int*)d_in[4];       // int32 [256]
    const uint8_t* init_res = (const uint8_t*)d_in[5];   // bool [256]
    const float* rW         = (const float*)d_in[6];     // f32 [10,256]
    const float* rb         = (const float*)d_in[7];     // f32 [10]
    float* out              = (float*)d_out;             // f32 [512,10]

    uint8_t* ws = (uint8_t*)d_ws;
    int*      flag = (int*)ws;                                        // 4 B
    uint32_t* xp   = (uint32_t*)(ws + 4096);                          // 1 MB
    uint16_t* T2   = (uint16_t*)(ws + 4096 + 1048576);                // 4 MB
    uint64_t* lp   = (uint64_t*)(ws + 4096 + 1048576 + 4194304);      // 8 MB

    detect_layout<<<1, 256, 0, stream>>>(x, flag);
    pack_x<<<(M_SAMP * S_STEPS * 32) / 256, 256, 0, stream>>>(x, flag, xp);
    build_T2<<<dim3(256, 32), 256, 0, stream>>>(wres, primes, flag, T2);
    pack_lut<<<4096, 256, 0, stream>>>(lut, (uint32_t*)lp);
    reservoir_wave<<<M_SAMP, 64, 0, stream>>>(xp, T2, lp, input_nodes, init_res,
                                              flag, rW, rb, out);
}

// Round 8
// 974.994 us; speedup vs baseline: 1.1351x; 1.1038x over previous
//
#include <hip/hip_runtime.h>
#include <stdint.h>

#define R_NODES 256
#define M_SAMP  512
#define S_STEPS 512
#define OUT_N   10

typedef unsigned int u32x2 __attribute__((ext_vector_type(2)));
typedef unsigned int u32x4 __attribute__((ext_vector_type(4)));

// ---------------- layout detection for bool inputs ----------------
// If bools were uploaded as int32, byte (4f+1) of every element is 0.
// If uploaded as uint8, ~half those bytes are 1.  flag=1 => uint8 layout.
__global__ void detect_layout(const uint8_t* __restrict__ x, int* __restrict__ flag) {
    __shared__ int any;
    if (threadIdx.x == 0) any = 0;
    __syncthreads();
    int acc = 0;
    for (int i = 0; i < 64; ++i)
        acc |= x[(size_t)(threadIdx.x * 64 + i) * 4 + 1];
    if (acc) atomicOr(&any, 1);
    __syncthreads();
    if (threadIdx.x == 0) *flag = any ? 1 : 0;
}

// ---------------- pack x bits: one uint32 per (m,s) ----------------
__global__ void pack_x(const uint8_t* __restrict__ x, const int* __restrict__ flag,
                       uint32_t* __restrict__ xp) {
    const int stride = (*flag) ? 1 : 4;
    const int f = blockIdx.x * blockDim.x + threadIdx.x;      // element idx, M*S*32 total
    const int val = x[(size_t)f * stride];
    const uint64_t mask = __ballot(val != 0);
    const int lane = threadIdx.x & 63;
    if ((lane & 31) == 0) {
        uint32_t w = (lane & 32) ? (uint32_t)(mask >> 32) : (uint32_t)mask;
        xp[f >> 5] = w;
    }
}

// ---------------- build nibble-chunk partial-sum table ----------------
// T1[(v*64 + c)*256 + j] = sum_{p: bit p of v} primes[4c+p] * W[j][4c+p]
// 16 vals x 64 chunks x 256 nodes x u16 = 512 KB -> L2-resident (4MB/XCD;
// R5 measured FETCH 507MB -> 7.8MB with this table).  Nibble for chunk c
// in the main kernel = state bits of nodes 4c..4c+3 (identity mapping).
// Per-chunk max sum <= 4*1619 = 6476: 4-row groups <= 25904, 8-row pairs
// <= 51808 < 2^16 -> packed-u16 adds can't overflow.
__global__ void build_T1(const uint8_t* __restrict__ wres, const int* __restrict__ primes,
                         const int* __restrict__ flag, uint16_t* __restrict__ T1) {
    const int v = blockIdx.x;          // 0..15 nibble value
    const int c = blockIdx.y;          // 0..63 chunk
    const int j = threadIdx.x;         // 0..255 node
    const int stride = (*flag) ? 1 : 4;
    int sum = 0;
#pragma unroll
    for (int p = 0; p < 4; ++p) {
        if ((v >> p) & 1) {
            const int k = c * 4 + p;
            if (wres[(size_t)(j * 256 + k) * stride]) sum += primes[k];
        }
    }
    T1[((size_t)v * 64 + c) * 256 + j] = (uint16_t)sum;
}

// ---------------- bit-pack the LUT: 256MB int32 -> 8MB bits ----------------
__device__ __forceinline__ uint32_t spread8(uint32_t x) {
    // bit i of low byte -> bit 4*i
    x = (x | (x << 12)) & 0x000F000Fu;
    x = (x | (x << 6))  & 0x03030303u;
    x = (x | (x << 3))  & 0x11111111u;
    return x;
}
__global__ void pack_lut(const int* __restrict__ lut, uint32_t* __restrict__ lp32) {
    const int lane = threadIdx.x & 63;
    const int gw = blockIdx.x * (blockDim.x >> 6) + (threadIdx.x >> 6); // 16384 waves
    const int4* src = (const int4*)lut;
    for (int it = 0; it < 16; ++it) {
        const int chunk = gw * 16 + it;                // 262144 wave-chunks total
        const int4 q = src[(size_t)chunk * 64 + lane]; // coalesced 16B/lane
        const uint64_t b0 = __ballot((q.x & 1) != 0);
        const uint64_t b1 = __ballot((q.y & 1) != 0);
        const uint64_t b2 = __ballot((q.z & 1) != 0);
        const uint64_t b3 = __ballot((q.w & 1) != 0);
        if (lane < 8) {
            const uint32_t B0 = (uint32_t)(b0 >> (8 * lane)) & 0xFF;
            const uint32_t B1 = (uint32_t)(b1 >> (8 * lane)) & 0xFF;
            const uint32_t B2 = (uint32_t)(b2 >> (8 * lane)) & 0xFF;
            const uint32_t B3 = (uint32_t)(b3 >> (8 * lane)) & 0xFF;
            const uint32_t w = spread8(B0) | (spread8(B1) << 1)
                             | (spread8(B2) << 2) | (spread8(B3) << 3);
            lp32[(size_t)chunk * 8 + lane] = w;
        }
    }
}

// ---------------- main reservoir scan: 8 WAVES per sample ----------------
// R4/R5/R6 evidence: a single wave sustains only ~4 VMEM instrs in flight
// -> wave-per-sample is MLP-starved at ~3200 cy/step no matter the table.
// Escape: split the per-step gather across 8 waves (each wave issues <=4
// dwordx4 = one L2 round-trip), tables L2-resident (R5-proven).
//   threads 0-255 own node t; ballots -> 8-word state mask in LDS -> B1
//   thread t: cg=t&31 (16B col block), rq=t>>5 (rows rq+16k, k=0..3);
//     4 x asm global_load_dwordx4 from T1, one vmcnt(0) trip
//   packed-u16 add 4 rows (<=25904/field), shfl_xor(32) pair-combine with
//     rows rq^1 (<=51808/field), lanes<32 publish part[w][256] -> B2
//   t<256: idx = sum of part[0..7][t] (8 u16 LDS reads, u32 accum), then
//     one lp (8MB, L2-hot) dwordx2 load -> new state bit.  2 barriers,
//     2 L2 trips, ~1250 cy/step target (vs 3150 measured single-wave).
__global__ __launch_bounds__(512, 1) void reservoir_block(
    const uint32_t* __restrict__ xp, const uint16_t* __restrict__ T1,
    const uint64_t* __restrict__ lp, const int* __restrict__ input_nodes,
    const uint8_t* __restrict__ init_res, const int* __restrict__ flag,
    const float* __restrict__ rW, const float* __restrict__ rb,
    float* __restrict__ out)
{
    const int m = blockIdx.x;
    const int t = threadIdx.x;          // 0..511
    const int l = t & 63;
    const int w = t >> 6;               // wave 0..7
    const int stride = (*flag) ? 1 : 4;

    __shared__ uint32_t smask[8];       // 256-bit state, bit n = node n
    __shared__ uint16_t part[8][256];   // per-wave partial col sums
    __shared__ uint32_t sxw[S_STEPS];
    __shared__ float    lout[OUT_N];

    const uint32_t* xrow = xp + m * S_STEPS;
    for (int i = t; i < S_STEPS; i += 512) sxw[i] = xrow[i];

    int slot = -1, v = 0;
    if (t < 256) {
        for (int i = 0; i < 32; ++i)
            if (input_nodes[i] == t) slot = i;
        v = init_res[(size_t)t * stride] ? 1 : 0;
    }

    const int cg  = t & 31;             // col block: cols cg*8..cg*8+7
    const int rq  = t >> 5;             // 0..15: rows rq, rq+16, rq+32, rq+48
    const int wb  = rq >> 3;            // mask word base for row rq+16k: wb+2k
    const int sh4 = (rq & 7) * 4;       // nibble shift within word

    const uint64_t t1base = (uint64_t)(uintptr_t)T1;
    const uint64_t lpbase = (uint64_t)(uintptr_t)lp;
    const uint32_t colb   = (uint32_t)cg << 4;

    __syncthreads();
    uint32_t xw = sxw[0];

    for (int s = 0; s < S_STEPS; ++s) {
        // ---- (1) state update + publish 256-bit mask ----
        if (t < 256) {
            if (slot >= 0) v = (xw >> slot) & 1;
            const uint64_t bal = __ballot(v != 0);
            if (l == 0) {
                smask[2 * w]     = (uint32_t)bal;
                smask[2 * w + 1] = (uint32_t)(bal >> 32);
            }
        }
        __syncthreads();                               // B1

        // ---- (2) gather: 4 x dwordx4 per thread, one L2 trip ----
        const uint32_t mw0 = smask[wb];
        const uint32_t mw1 = smask[wb + 2];
        const uint32_t mw2 = smask[wb + 4];
        const uint32_t mw3 = smask[wb + 6];
        const uint32_t o0 = (((mw0 >> sh4) & 0xFu) << 15) | ((uint32_t)(rq     ) << 9) | colb;
        const uint32_t o1 = (((mw1 >> sh4) & 0xFu) << 15) | ((uint32_t)(rq + 16) << 9) | colb;
        const uint32_t o2 = (((mw2 >> sh4) & 0xFu) << 15) | ((uint32_t)(rq + 32) << 9) | colb;
        const uint32_t o3 = (((mw3 >> sh4) & 0xFu) << 15) | ((uint32_t)(rq + 48) << 9) | colb;
        u32x4 d0, d1, d2, d3;
        asm volatile("global_load_dwordx4 %0, %1, %2" : "=v"(d0) : "v"(o0), "s"(t1base));
        asm volatile("global_load_dwordx4 %0, %1, %2" : "=v"(d1) : "v"(o1), "s"(t1base));
        asm volatile("global_load_dwordx4 %0, %1, %2" : "=v"(d2) : "v"(o2), "s"(t1base));
        asm volatile("global_load_dwordx4 %0, %1, %2" : "=v"(d3) : "v"(o3), "s"(t1base));
        const uint32_t xw_next = sxw[(s + 1 < S_STEPS) ? s + 1 : s];
        asm volatile("s_waitcnt vmcnt(0)");
        asm volatile("" : "+v"(d0), "+v"(d1), "+v"(d2), "+v"(d3));

        // ---- (3) packed add 4 rows + pair-combine (rows rq^1 via lane^32) --
        u32x4 sm;
        sm[0] = d0[0] + d1[0] + d2[0] + d3[0];
        sm[1] = d0[1] + d1[1] + d2[1] + d3[1];
        sm[2] = d0[2] + d1[2] + d2[2] + d3[2];
        sm[3] = d0[3] + d1[3] + d2[3] + d3[3];
        sm[0] += (uint32_t)__shfl_xor((int)sm[0], 32, 64);
        sm[1] += (uint32_t)__shfl_xor((int)sm[1], 32, 64);
        sm[2] += (uint32_t)__shfl_xor((int)sm[2], 32, 64);
        sm[3] += (uint32_t)__shfl_xor((int)sm[3], 32, 64);
        if (l < 32) *(u32x4*)&part[w][cg * 8] = sm;
        __syncthreads();                               // B2

        // ---- (4) reduce 8 partials + LUT bit lookup (t<256) ----
        if (t < 256) {
            uint32_t idx = 0;
#pragma unroll
            for (int q = 0; q < 8; ++q) idx += (uint32_t)part[q][t];
            u32x2 wv;
            const uint32_t o = ((uint32_t)t << 15) + ((idx >> 6) << 3);
            asm volatile("global_load_dwordx2 %0, %1, %2" : "=v"(wv) : "v"(o), "s"(lpbase));
            asm volatile("s_waitcnt vmcnt(0)");
            asm volatile("" : "+v"(wv));
            v = (int)(((((uint64_t)wv[1] << 32) | wv[0]) >> (idx & 63)) & 1);
        }
        xw = xw_next;
    }

    // keep the readout loads from being hoisted into the counted loop
    const float* rWo;
    const float* rbo;
    asm volatile("" : "=s"(rWo) : "0"(rW));
    asm volatile("" : "=s"(rbo) : "0"(rb));

    // readout: out[m][o] = b[o] + sum_j v_j * W[o][j]
    __syncthreads();
    if (t < OUT_N) lout[t] = 0.f;
    __syncthreads();
    if (t < 256) {
#pragma unroll
        for (int o = 0; o < OUT_N; ++o) {
            float c = v ? rWo[o * R_NODES + t] : 0.f;
#pragma unroll
            for (int off = 32; off > 0; off >>= 1)
                c += __shfl_down(c, off, 64);
            if (l == 0) atomicAdd(&lout[o], c);
        }
    }
    __syncthreads();
    if (t < OUT_N) out[m * OUT_N + t] = lout[t] + rbo[t];
}

extern "C" void kernel_launch(void* const* d_in, const int* in_sizes, int n_in,
                              void* d_out, int out_size, void* d_ws, size_t ws_size,
                              hipStream_t stream) {
    const uint8_t* x        = (const uint8_t*)d_in[0];   // bool [M,S,D,B]
    const int* input_nodes  = (const int*)d_in[1];       // int32 [32]
    const int* lut          = (const int*)d_in[2];       // int32 [256, 2^18]
    const uint8_t* wres     = (const uint8_t*)d_in[3];   // bool [256,256]
    const int* primes       = (const int*)d_in[4];       // int32 [256]
    const uint8_t* init_res = (const uint8_t*)d_in[5];   // bool [256]
    const float* rW         = (const float*)d_in[6];     // f32 [10,256]
    const float* rb         = (const float*)d_in[7];     // f32 [10]
    float* out              = (float*)d_out;             // f32 [512,10]

    uint8_t* ws = (uint8_t*)d_ws;
    int*      flag = (int*)ws;                                        // 4 B
    uint32_t* xp   = (uint32_t*)(ws + 4096);                          // 1 MB
    uint16_t* T1   = (uint16_t*)(ws + 4096 + 1048576);                // 512 KB
    uint64_t* lp   = (uint64_t*)(ws + 4096 + 1048576 + 524288);       // 8 MB

    detect_layout<<<1, 256, 0, stream>>>(x, flag);
    pack_x<<<(M_SAMP * S_STEPS * 32) / 256, 256, 0, stream>>>(x, flag, xp);
    build_T1<<<dim3(16, 64), 256, 0, stream>>>(wres, primes, flag, T1);
    pack_lut<<<4096, 256, 0, stream>>>(lut, (uint32_t*)lp);
    reservoir_block<<<M_SAMP, 512, 0, stream>>>(xp, T1, lp, input_nodes, init_res,
                                                flag, rW, rb, out);
}